// Round 2
// baseline (222.439 us; speedup 1.0000x reference)
//
#include <hip/hip_runtime.h>
#include <hip/hip_bf16.h>
#include <type_traits>

#define B_  2
#define T_  2048
#define D_  1024
#define H_  16
#define HD_ 64

typedef __attribute__((ext_vector_type(8))) short bf16x8;
typedef __attribute__((ext_vector_type(4))) float f32x4;

__device__ __forceinline__ unsigned short f2b(float x) {
  union { __hip_bfloat16 h; unsigned short u; } c;
  c.h = __float2bfloat16(x);
  return c.u;
}
__device__ __forceinline__ float b2f(unsigned short u) {
  union { unsigned short u; __hip_bfloat16 h; } c;
  c.u = u;
  return __bfloat162float(c.h);
}

__device__ __forceinline__ void ld_g2l_16(const unsigned short* g, unsigned short* l) {
  auto gp = (const __attribute__((address_space(1))) unsigned int*)g;
  auto lp = (__attribute__((address_space(3))) unsigned int*)l;
  __builtin_amdgcn_global_load_lds(gp, lp, 16, 0, 0);
}

// ---------------- cast fp32 -> bf16: x (4M) and packed weights (4x1M) -------
__global__ void __launch_bounds__(256)
cast_all(const float* __restrict__ x, const float* __restrict__ wq,
         const float* __restrict__ wk, const float* __restrict__ wv,
         const float* __restrict__ wo, unsigned short* __restrict__ xb,
         unsigned short* __restrict__ wp) {
  int blk = blockIdx.x;
  const float* src;
  unsigned short* dst;
  size_t off;
  if (blk < 2048) {
    src = x; dst = xb; off = (size_t)blk * 2048;
  } else {
    int t = (blk - 2048) >> 9;
    int r = (blk - 2048) & 511;
    src = (t == 0) ? wq : (t == 1) ? wk : (t == 2) ? wv : wo;
    dst = wp + (size_t)t * 1048576;
    off = (size_t)r * 2048;
  }
  size_t i = off + threadIdx.x * 8;
  float4 a = *(const float4*)(src + i);
  float4 b = *(const float4*)(src + i + 4);
  unsigned short h[8] = {f2b(a.x), f2b(a.y), f2b(a.z), f2b(a.w),
                         f2b(b.x), f2b(b.y), f2b(b.z), f2b(b.w)};
  *(uint4*)(dst + i) = *(uint4*)h;
}

// ---------------- MFMA NT GEMM core, async double-buffered ------------------
// C[MROWS,128] = A @ B^T. BK=32, global_load_lds(16B), 4 waves as 2x2.
// rope_mode: 0=none, 1=K (rope), 2=Q (rope + log2e/8 scale). tok0 = token base.
template <typename OutT, int MROWS>
__device__ __forceinline__ void gemm_core(const unsigned short* __restrict__ A,
                                          const unsigned short* __restrict__ Bw,
                                          OutT* __restrict__ C, int K, int Ldc,
                                          int rope_mode, const float* __restrict__ cosT,
                                          const float* __restrict__ sinT, int tok0) {
  constexpr int MT = MROWS / 32;
  __shared__ unsigned short a_s[2][MROWS * 32];  // no pad (global_load_lds)
  __shared__ unsigned short b_s[2][128 * 32];
  const int tid = threadIdx.x;
  const int lane = tid & 63;
  const int w = tid >> 6;
  const int m16 = lane & 15;
  const int quad = lane >> 4;
  const int wm = w >> 1, wn = w & 1;
  const int rl = lane >> 2;            // row within 16-row segment
  const int cl = (lane & 3) * 8;       // bf16 col offset (16 B chunks)

  f32x4 acc[MT][4];
#pragma unroll
  for (int i = 0; i < MT; i++)
#pragma unroll
    for (int j = 0; j < 4; j++) acc[i][j] = (f32x4){0.f, 0.f, 0.f, 0.f};

  auto stage = [&](int it, int bs) {
    int k0 = it * 32;
#pragma unroll
    for (int t = 0; t < MROWS / 64; t++) {
      int seg = w * 16 + t * 64;
      ld_g2l_16(A + (size_t)(seg + rl) * K + k0 + cl, &a_s[bs][seg * 32]);
    }
#pragma unroll
    for (int j2 = 0; j2 < 2; j2++) {
      int seg = w * 32 + j2 * 16;
      ld_g2l_16(Bw + (size_t)(seg + rl) * K + k0 + cl, &b_s[bs][seg * 32]);
    }
  };

  const int nit = K / 32;
  stage(0, 0);
  __syncthreads();
  for (int it = 0; it < nit; it++) {
    int cur = it & 1;
    if (it + 1 < nit) stage(it + 1, cur ^ 1);   // flies under compute
    bf16x8 af[MT], bfr[4];
#pragma unroll
    for (int mt = 0; mt < MT; mt++)
      af[mt] = *(const bf16x8*)&a_s[cur][(wm * (MT * 16) + mt * 16 + m16) * 32 + quad * 8];
#pragma unroll
    for (int nt = 0; nt < 4; nt++)
      bfr[nt] = *(const bf16x8*)&b_s[cur][(wn * 64 + nt * 16 + m16) * 32 + quad * 8];
#pragma unroll
    for (int mt = 0; mt < MT; mt++)
#pragma unroll
      for (int nt = 0; nt < 4; nt++)
        acc[mt][nt] = __builtin_amdgcn_mfma_f32_16x16x32_bf16(af[mt], bfr[nt], acc[mt][nt], 0, 0, 0);
    __syncthreads();
  }

  // fused RoPE epilogue: partner of col d is d^32 -> frag nt^2, same lane.
  if (rope_mode) {
    // Q side: fold softmax 1/sqrt(HD)=0.125 AND log2(e) so attn can use exp2
    float scale = (rope_mode == 2) ? 0.18033688011112042f : 1.f;
#pragma unroll
    for (int mt = 0; mt < MT; mt++)
#pragma unroll
      for (int reg = 0; reg < 4; reg++) {
        int t = (tok0 + wm * (MT * 16) + mt * 16 + quad * 4 + reg) & (T_ - 1);
#pragma unroll
        for (int nt = 0; nt < 2; nt++) {
          int d = nt * 16 + m16;                 // < 32
          float co = cosT[t * HD_ + d] * scale;
          float si = sinT[t * HD_ + d] * scale;  // sin/cos same at d and d+32
          float lo = acc[mt][nt][reg], hi = acc[mt][nt + 2][reg];
          acc[mt][nt][reg]     = lo * co - hi * si;
          acc[mt][nt + 2][reg] = hi * co + lo * si;
        }
      }
  }
#pragma unroll
  for (int mt = 0; mt < MT; mt++)
#pragma unroll
    for (int nt = 0; nt < 4; nt++)
#pragma unroll
      for (int reg = 0; reg < 4; reg++) {
        OutT* p = C + (size_t)(wm * (MT * 16) + mt * 16 + quad * 4 + reg) * Ldc + wn * 64 + nt * 16 + m16;
        if constexpr (std::is_same_v<OutT, float>) *p = acc[mt][nt][reg];
        else *p = f2b(acc[mt][nt][reg]);
      }
}

// fused QKV + RoPE: Bw = packed [3072,1024] (wq|wk|wv)
__global__ void __launch_bounds__(256)
gemm_qkv(const unsigned short* __restrict__ xb, const unsigned short* __restrict__ wp,
         unsigned short* __restrict__ qkv, const float* __restrict__ cosT,
         const float* __restrict__ sinT) {
  const int nb = blockIdx.x;           // 0..23
  const int bm = blockIdx.y * 128;
  const int mi = nb >> 3;
  const int bn = (nb & 7) * 128;
  const int rope_mode = (mi == 0) ? 2 : (mi == 1) ? 1 : 0;
  gemm_core<unsigned short, 128>(xb + (size_t)bm * D_,
                                 wp + (size_t)(mi * 1024 + bn) * D_,
                                 qkv + (size_t)mi * (4096ull * D_) + (size_t)bm * D_ + bn,
                                 D_, D_, rope_mode, cosT, sinT, bm);
}

__global__ void __launch_bounds__(256)
gemm_out(const unsigned short* __restrict__ Ab, const unsigned short* __restrict__ wob,
         float* __restrict__ C) {
  const int bn = blockIdx.x * 128;
  const int bm = blockIdx.y * 64;
  gemm_core<float, 64>(Ab + (size_t)bm * D_, wob + (size_t)bn * D_,
                       C + (size_t)bm * D_ + bn, D_, D_, 0, nullptr, nullptr, 0);
}

// ---------------- V -> V^T  (VT[b][h][d][t]) --------------------------------
__global__ void __launch_bounds__(256)
vtrans(const unsigned short* __restrict__ V, unsigned short* __restrict__ VT) {
  __shared__ unsigned short tile[64][72];
  const int tid = threadIdx.x;
  const int tb = blockIdx.x, h = blockIdx.y, b = blockIdx.z;
  const unsigned short* Vb = V + ((size_t)b * T_ + tb * 64) * D_ + h * HD_;
  int r = tid >> 2;
  int c = (tid & 3) * 16;
  bf16x8 v0 = *(const bf16x8*)(Vb + (size_t)r * D_ + c);
  bf16x8 v1 = *(const bf16x8*)(Vb + (size_t)r * D_ + c + 8);
#pragma unroll
  for (int e = 0; e < 8; e++) tile[c + e][r] = ((unsigned short*)&v0)[e];
#pragma unroll
  for (int e = 0; e < 8; e++) tile[c + 8 + e][r] = ((unsigned short*)&v1)[e];
  __syncthreads();
  unsigned short* VTb = VT + ((size_t)b * H_ + h) * HD_ * T_ + tb * 64;
  *(bf16x8*)(VTb + (size_t)r * T_ + c)     = *(const bf16x8*)&tile[r][c];
  *(bf16x8*)(VTb + (size_t)r * T_ + c + 8) = *(const bf16x8*)&tile[r][c + 8];
}

// ---------------- MFMA flash attention, S^T form, 3-deep async K/V ----------
// 512 threads = 8 waves x 16 q-rows (128-row q-tile). K and V^T tiles staged
// by global_load_lds with XOR-swizzled source chunks (phys chunk = lc ^ (r&7)).
// T15 double-pipeline: QK^T(t+1) issues before softmax(t) so the MFMA cluster
// overlaps the softmax VALU chain. 3 LDS buffers: consume t / QK t+1 / DMA t+2.
__global__ void __launch_bounds__(512, 4)
attn_kernel(const unsigned short* __restrict__ Q, const unsigned short* __restrict__ K,
            const unsigned short* __restrict__ VT, unsigned short* __restrict__ O) {
  __shared__ __align__(16) unsigned short qp_s[128][72];   // Q tile / P^T / O staging
  __shared__ __align__(16) unsigned short k_s[3][64 * 64]; // row-major 64x64, swizzled
  __shared__ __align__(16) unsigned short vt_s[3][64 * 64];

  const int tid = threadIdx.x;
  const int lane = tid & 63;
  const int w = tid >> 6;              // 0..7
  const int m16 = lane & 15;
  const int quad = lane >> 4;
  const int swz = m16 & 7;
  const int pc0 = quad ^ swz;          // physical chunk for k-step 0
  const int pc1 = pc0 ^ 4;             // k-step 1

  // causal-balanced block mapping
  int x = blockIdx.x;
  int bh, qb;
  if (x < 256) { bh = x >> 4; qb = x & 15; }
  else         { bh = 16 + ((x - 256) >> 4); qb = 15 - ((x - 256) & 15); }
  const int b = bh >> 4, h = bh & 15;
  const int q0 = qb * 128;

  const unsigned short* Qb = Q + ((size_t)b * T_ + q0) * D_ + h * HD_;
  const unsigned short* Kb = K + (size_t)b * T_ * D_ + h * HD_;
  const unsigned short* VTb = VT + ((size_t)b * H_ + h) * HD_ * T_;

  // stage Q tile (manual, padded LDS)
#pragma unroll
  for (int i = 0; i < 2; i++) {
    int idx = tid + i * 512;
    int r = idx >> 3, c = idx & 7;
    *(bf16x8*)&qp_s[r][c * 8] = *(const bf16x8*)(Qb + (size_t)r * D_ + c * 8);
  }

  // async stage of K/VT tile kt: wave w covers rows w*8..w*8+7
  auto stage_kv = [&](int kt, int bs) {
    int r_sub = lane >> 3, c = lane & 7;
    int cs = (c ^ r_sub) * 8;                 // XOR-swizzled source chunk
    int gr = w * 8 + r_sub;
    ld_g2l_16(Kb + (size_t)(kt * 64 + gr) * D_ + cs, &k_s[bs][w * 8 * 64]);
    ld_g2l_16(VTb + (size_t)gr * T_ + kt * 64 + cs, &vt_s[bs][w * 8 * 64]);
  };

  f32x4 o_acc[4];
#pragma unroll
  for (int dt = 0; dt < 4; dt++) o_acc[dt] = (f32x4){0.f, 0.f, 0.f, 0.f};
  float m_i = -1e30f, l_i = 0.f;
  const int rg = q0 + w * 16 + m16;
  const int rmax = q0 + w * 16 + 15;
  const int ktmax = (q0 + 127) >> 6;   // >= 1 always

  stage_kv(0, 0);
  stage_kv(1, 1);
  __syncthreads();   // publishes Q tile + K/V tiles 0,1
  bf16x8 q_frag[2];
  q_frag[0] = *(const bf16x8*)&qp_s[w * 16 + m16][quad * 8];
  q_frag[1] = *(const bf16x8*)&qp_s[w * 16 + m16][32 + quad * 8];

  // S^T = K Q^T for one 64-key tile
  auto qk = [&](f32x4* sf, const unsigned short* kc) {
    __builtin_amdgcn_s_setprio(1);
#pragma unroll
    for (int jt = 0; jt < 4; jt++) {
      bf16x8 a0 = *(const bf16x8*)&kc[(jt * 16 + m16) * 64 + pc0 * 8];
      bf16x8 a1 = *(const bf16x8*)&kc[(jt * 16 + m16) * 64 + pc1 * 8];
      f32x4 acc = (f32x4){0.f, 0.f, 0.f, 0.f};
      acc = __builtin_amdgcn_mfma_f32_16x16x32_bf16(a0, q_frag[0], acc, 0, 0, 0);
      acc = __builtin_amdgcn_mfma_f32_16x16x32_bf16(a1, q_frag[1], acc, 0, 0, 0);
      sf[jt] = acc;
    }
    __builtin_amdgcn_s_setprio(0);
  };

  f32x4 sf[4];
  qk(sf, &k_s[0][0]);                  // S(0)

  for (int t = 0; t <= ktmax; t++) {
    if (t + 2 <= ktmax) stage_kv(t + 2, (t + 2) % 3);   // DMA two tiles ahead
    f32x4 sfn[4];
    const bool hn = (t + 1 <= ktmax) && ((t + 1) * 64 <= rmax);
    if (hn) qk(sfn, &k_s[(t + 1) % 3][0]);  // QK^T(t+1) overlaps softmax(t)

    if (t * 64 <= rmax) {
      const unsigned short* vc = &vt_s[t % 3][0];
      if (t * 64 + 63 > q0 + w * 16) {   // causal mask
#pragma unroll
        for (int jt = 0; jt < 4; jt++)
#pragma unroll
          for (int reg = 0; reg < 4; reg++) {
            int jg = t * 64 + jt * 16 + quad * 4 + reg;
            if (jg > rg) sf[jt][reg] = -1e30f;
          }
      }
      // online softmax in base-2 (per-lane row, 2 cross-quad shfls)
      float mx = sf[0][0];
#pragma unroll
      for (int jt = 0; jt < 4; jt++)
#pragma unroll
        for (int reg = 0; reg < 4; reg++) mx = fmaxf(mx, sf[jt][reg]);
      mx = fmaxf(mx, __shfl_xor(mx, 16, 64));
      mx = fmaxf(mx, __shfl_xor(mx, 32, 64));
      // T13 defer-max: skip O-rescale while max grows < 8 (P bounded by 2^8)
      if (!__all(mx <= m_i + 8.f)) {
        float mn = fmaxf(m_i, mx);
        float alpha = exp2f(m_i - mn);
        l_i *= alpha;
#pragma unroll
        for (int dt = 0; dt < 4; dt++)
#pragma unroll
          for (int reg = 0; reg < 4; reg++) o_acc[dt][reg] *= alpha;
        m_i = mn;
      }
      float lt = 0.f;
      float p[4][4];
#pragma unroll
      for (int jt = 0; jt < 4; jt++)
#pragma unroll
        for (int reg = 0; reg < 4; reg++) {
          p[jt][reg] = exp2f(sf[jt][reg] - m_i);
          lt += p[jt][reg];
        }
      // P^T rows -> qp_s (wave-private)
#pragma unroll
      for (int jt = 0; jt < 4; jt++) {
        unsigned short pk[4] = {f2b(p[jt][0]), f2b(p[jt][1]), f2b(p[jt][2]), f2b(p[jt][3])};
        *(uint2*)&qp_s[w * 16 + m16][jt * 16 + quad * 4] = *(uint2*)pk;
      }
      bf16x8 bp0 = *(const bf16x8*)&qp_s[w * 16 + m16][quad * 8];
      bf16x8 bp1 = *(const bf16x8*)&qp_s[w * 16 + m16][32 + quad * 8];
      // O^T += V^T P^T
      __builtin_amdgcn_s_setprio(1);
#pragma unroll
      for (int dt = 0; dt < 4; dt++) {
        int rowd = dt * 16 + m16;
        bf16x8 a0 = *(const bf16x8*)&vc[rowd * 64 + pc0 * 8];
        bf16x8 a1 = *(const bf16x8*)&vc[rowd * 64 + pc1 * 8];
        o_acc[dt] = __builtin_amdgcn_mfma_f32_16x16x32_bf16(a0, bp0, o_acc[dt], 0, 0, 0);
        o_acc[dt] = __builtin_amdgcn_mfma_f32_16x16x32_bf16(a1, bp1, o_acc[dt], 0, 0, 0);
      }
      __builtin_amdgcn_s_setprio(0);
      // l-reduction deferred so the 2 shfls overlap PV MFMAs
      lt += __shfl_xor(lt, 16, 64);
      lt += __shfl_xor(lt, 32, 64);
      l_i += lt;
    }
    if (hn) {
#pragma unroll
      for (int jt = 0; jt < 4; jt++) sf[jt] = sfn[jt];
    }
    __syncthreads();   // publishes DMA'd tile t+2, protects buffer reuse
  }

  // epilogue: normalize, transpose via LDS, coalesced stores
  float inv = 1.f / l_i;
#pragma unroll
  for (int dt = 0; dt < 4; dt++) {
    unsigned short ok[4];
#pragma unroll
    for (int reg = 0; reg < 4; reg++) ok[reg] = f2b(o_acc[dt][reg] * inv);
    *(uint2*)&qp_s[w * 16 + m16][dt * 16 + quad * 4] = *(uint2*)ok;
  }
  __syncthreads();
  unsigned short* Ob = O + ((size_t)b * T_ + q0) * D_ + h * HD_;
#pragma unroll
  for (int i = 0; i < 2; i++) {
    int idx = tid + i * 512;
    int r = idx >> 3, c = idx & 7;
    *(bf16x8*)(Ob + (size_t)r * D_ + c * 8) = *(const bf16x8*)&qp_s[r][c * 8];
  }
}

extern "C" void kernel_launch(void* const* d_in, const int* in_sizes, int n_in,
                              void* d_out, int out_size, void* d_ws, size_t ws_size,
                              hipStream_t stream) {
  const float* x    = (const float*)d_in[0];
  const float* wq   = (const float*)d_in[1];
  const float* wk   = (const float*)d_in[2];
  const float* wv   = (const float*)d_in[3];
  const float* wo   = (const float*)d_in[4];
  const float* cosT = (const float*)d_in[5];
  const float* sinT = (const float*)d_in[6];
  float* out = (float*)d_out;

  const size_t NTOK = (size_t)B_ * T_;   // 4096
  const size_t SZ   = NTOK * D_;         // 4M elements
  unsigned short* xb   = (unsigned short*)d_ws;   // 8 MB (dead after gemm_qkv)
  unsigned short* Wp   = xb + SZ;                 // 8 MB (wq|wk|wv|wo)
  unsigned short* QKVh = Wp + 4 * 1048576;        // 24 MB (Q|K|V)
  unsigned short* Ab   = QKVh + 3 * SZ;           // 8 MB
  unsigned short* VTb  = xb;                      // reuse xb for V^T

  cast_all<<<4096, 256, 0, stream>>>(x, wq, wk, wv, wo, xb, Wp);
  gemm_qkv<<<dim3(24, 32), 256, 0, stream>>>(xb, Wp, QKVh, cosT, sinT);
  vtrans<<<dim3(32, 16, 2), 256, 0, stream>>>(QKVh + 2 * SZ, VTb);
  attn_kernel<<<512, 512, 0, stream>>>(QKVh, QKVh + SZ, VTb, Ab);
  gemm_out<<<dim3(8, 64), 256, 0, stream>>>(Ab, Wp + 3 * 1048576, out);
}

// Round 3
// 203.170 us; speedup vs baseline: 1.0948x; 1.0948x over previous
//
#include <hip/hip_runtime.h>
#include <hip/hip_bf16.h>
#include <type_traits>

#define B_  2
#define T_  2048
#define D_  1024
#define H_  16
#define HD_ 64

typedef __attribute__((ext_vector_type(8))) short bf16x8;
typedef __attribute__((ext_vector_type(4))) float f32x4;

__device__ __forceinline__ unsigned short f2b(float x) {
  union { __hip_bfloat16 h; unsigned short u; } c;
  c.h = __float2bfloat16(x);
  return c.u;
}
__device__ __forceinline__ float b2f(unsigned short u) {
  union { unsigned short u; __hip_bfloat16 h; } c;
  c.u = u;
  return __bfloat162float(c.h);
}

__device__ __forceinline__ void ld_g2l_16(const unsigned short* g, unsigned short* l) {
  auto gp = (const __attribute__((address_space(1))) unsigned int*)g;
  auto lp = (__attribute__((address_space(3))) unsigned int*)l;
  __builtin_amdgcn_global_load_lds(gp, lp, 16, 0, 0);
}

// ---------------- cast fp32 -> bf16: x (4M) and packed weights (4x1M) -------
__global__ void __launch_bounds__(256)
cast_all(const float* __restrict__ x, const float* __restrict__ wq,
         const float* __restrict__ wk, const float* __restrict__ wv,
         const float* __restrict__ wo, unsigned short* __restrict__ xb,
         unsigned short* __restrict__ wp) {
  int blk = blockIdx.x;
  const float* src;
  unsigned short* dst;
  size_t off;
  if (blk < 2048) {
    src = x; dst = xb; off = (size_t)blk * 2048;
  } else {
    int t = (blk - 2048) >> 9;
    int r = (blk - 2048) & 511;
    src = (t == 0) ? wq : (t == 1) ? wk : (t == 2) ? wv : wo;
    dst = wp + (size_t)t * 1048576;
    off = (size_t)r * 2048;
  }
  size_t i = off + threadIdx.x * 8;
  float4 a = *(const float4*)(src + i);
  float4 b = *(const float4*)(src + i + 4);
  unsigned short h[8] = {f2b(a.x), f2b(a.y), f2b(a.z), f2b(a.w),
                         f2b(b.x), f2b(b.y), f2b(b.z), f2b(b.w)};
  *(uint4*)(dst + i) = *(uint4*)h;
}

// ---------------- MFMA NT GEMM core, async double-buffered ------------------
// C[MROWS,128] = A @ B^T. BK=32, global_load_lds(16B), 4 waves as 2x2.
// rope_mode: 0=none, 1=K (rope), 2=Q (rope + log2e/8 scale). tok0 = token base.
template <typename OutT, int MROWS>
__device__ __forceinline__ void gemm_core(const unsigned short* __restrict__ A,
                                          const unsigned short* __restrict__ Bw,
                                          OutT* __restrict__ C, int K, int Ldc,
                                          int rope_mode, const float* __restrict__ cosT,
                                          const float* __restrict__ sinT, int tok0) {
  constexpr int MT = MROWS / 32;
  __shared__ unsigned short a_s[2][MROWS * 32];  // no pad (global_load_lds)
  __shared__ unsigned short b_s[2][128 * 32];
  const int tid = threadIdx.x;
  const int lane = tid & 63;
  const int w = tid >> 6;
  const int m16 = lane & 15;
  const int quad = lane >> 4;
  const int wm = w >> 1, wn = w & 1;
  const int rl = lane >> 2;            // row within 16-row segment
  const int cl = (lane & 3) * 8;       // bf16 col offset (16 B chunks)

  f32x4 acc[MT][4];
#pragma unroll
  for (int i = 0; i < MT; i++)
#pragma unroll
    for (int j = 0; j < 4; j++) acc[i][j] = (f32x4){0.f, 0.f, 0.f, 0.f};

  auto stage = [&](int it, int bs) {
    int k0 = it * 32;
#pragma unroll
    for (int t = 0; t < MROWS / 64; t++) {
      int seg = w * 16 + t * 64;
      ld_g2l_16(A + (size_t)(seg + rl) * K + k0 + cl, &a_s[bs][seg * 32]);
    }
#pragma unroll
    for (int j2 = 0; j2 < 2; j2++) {
      int seg = w * 32 + j2 * 16;
      ld_g2l_16(Bw + (size_t)(seg + rl) * K + k0 + cl, &b_s[bs][seg * 32]);
    }
  };

  const int nit = K / 32;
  stage(0, 0);
  __syncthreads();
  for (int it = 0; it < nit; it++) {
    int cur = it & 1;
    if (it + 1 < nit) stage(it + 1, cur ^ 1);   // flies under compute
    bf16x8 af[MT], bfr[4];
#pragma unroll
    for (int mt = 0; mt < MT; mt++)
      af[mt] = *(const bf16x8*)&a_s[cur][(wm * (MT * 16) + mt * 16 + m16) * 32 + quad * 8];
#pragma unroll
    for (int nt = 0; nt < 4; nt++)
      bfr[nt] = *(const bf16x8*)&b_s[cur][(wn * 64 + nt * 16 + m16) * 32 + quad * 8];
#pragma unroll
    for (int mt = 0; mt < MT; mt++)
#pragma unroll
      for (int nt = 0; nt < 4; nt++)
        acc[mt][nt] = __builtin_amdgcn_mfma_f32_16x16x32_bf16(af[mt], bfr[nt], acc[mt][nt], 0, 0, 0);
    __syncthreads();
  }

  // fused RoPE epilogue: partner of col d is d^32 -> frag nt^2, same lane.
  if (rope_mode) {
    // Q side: fold softmax 1/sqrt(HD)=0.125 AND log2(e) so attn can use exp2
    float scale = (rope_mode == 2) ? 0.18033688011112042f : 1.f;
#pragma unroll
    for (int mt = 0; mt < MT; mt++)
#pragma unroll
      for (int reg = 0; reg < 4; reg++) {
        int t = (tok0 + wm * (MT * 16) + mt * 16 + quad * 4 + reg) & (T_ - 1);
#pragma unroll
        for (int nt = 0; nt < 2; nt++) {
          int d = nt * 16 + m16;                 // < 32
          float co = cosT[t * HD_ + d] * scale;
          float si = sinT[t * HD_ + d] * scale;  // sin/cos same at d and d+32
          float lo = acc[mt][nt][reg], hi = acc[mt][nt + 2][reg];
          acc[mt][nt][reg]     = lo * co - hi * si;
          acc[mt][nt + 2][reg] = hi * co + lo * si;
        }
      }
  }
#pragma unroll
  for (int mt = 0; mt < MT; mt++)
#pragma unroll
    for (int nt = 0; nt < 4; nt++)
#pragma unroll
      for (int reg = 0; reg < 4; reg++) {
        OutT* p = C + (size_t)(wm * (MT * 16) + mt * 16 + quad * 4 + reg) * Ldc + wn * 64 + nt * 16 + m16;
        if constexpr (std::is_same_v<OutT, float>) *p = acc[mt][nt][reg];
        else *p = f2b(acc[mt][nt][reg]);
      }
}

// fused QKV + RoPE: Bw = packed [3072,1024] (wq|wk|wv)
__global__ void __launch_bounds__(256)
gemm_qkv(const unsigned short* __restrict__ xb, const unsigned short* __restrict__ wp,
         unsigned short* __restrict__ qkv, const float* __restrict__ cosT,
         const float* __restrict__ sinT) {
  const int nb = blockIdx.x;           // 0..23
  const int bm = blockIdx.y * 128;
  const int mi = nb >> 3;
  const int bn = (nb & 7) * 128;
  const int rope_mode = (mi == 0) ? 2 : (mi == 1) ? 1 : 0;
  gemm_core<unsigned short, 128>(xb + (size_t)bm * D_,
                                 wp + (size_t)(mi * 1024 + bn) * D_,
                                 qkv + (size_t)mi * (4096ull * D_) + (size_t)bm * D_ + bn,
                                 D_, D_, rope_mode, cosT, sinT, bm);
}

__global__ void __launch_bounds__(256)
gemm_out(const unsigned short* __restrict__ Ab, const unsigned short* __restrict__ wob,
         float* __restrict__ C) {
  const int bn = blockIdx.x * 128;
  const int bm = blockIdx.y * 64;
  gemm_core<float, 64>(Ab + (size_t)bm * D_, wob + (size_t)bn * D_,
                       C + (size_t)bm * D_ + bn, D_, D_, 0, nullptr, nullptr, 0);
}

// ---------------- V -> V^T  (VT[b][h][d][t]) --------------------------------
__global__ void __launch_bounds__(256)
vtrans(const unsigned short* __restrict__ V, unsigned short* __restrict__ VT) {
  __shared__ unsigned short tile[64][72];
  const int tid = threadIdx.x;
  const int tb = blockIdx.x, h = blockIdx.y, b = blockIdx.z;
  const unsigned short* Vb = V + ((size_t)b * T_ + tb * 64) * D_ + h * HD_;
  int r = tid >> 2;
  int c = (tid & 3) * 16;
  bf16x8 v0 = *(const bf16x8*)(Vb + (size_t)r * D_ + c);
  bf16x8 v1 = *(const bf16x8*)(Vb + (size_t)r * D_ + c + 8);
#pragma unroll
  for (int e = 0; e < 8; e++) tile[c + e][r] = ((unsigned short*)&v0)[e];
#pragma unroll
  for (int e = 0; e < 8; e++) tile[c + 8 + e][r] = ((unsigned short*)&v1)[e];
  __syncthreads();
  unsigned short* VTb = VT + ((size_t)b * H_ + h) * HD_ * T_ + tb * 64;
  *(bf16x8*)(VTb + (size_t)r * T_ + c)     = *(const bf16x8*)&tile[r][c];
  *(bf16x8*)(VTb + (size_t)r * T_ + c + 8) = *(const bf16x8*)&tile[r][c + 8];
}

// ---------------- MFMA flash attention, S^T form, async dbuf K/V ------------
// 256 threads = 4 waves x 16 q-rows (64-row q-tile), 1024 blocks -> 3+/CU so
// independent barrier streams overlap softmax VALU with MFMA/DS of others.
// Heavy-first mapping (qt = 31 - x>>5) gives LPT backfill; bh = x&31 pins all
// blocks of a head to one XCD (x%8 == bh%8) for K/V L2 locality.
__global__ void __launch_bounds__(256, 3)
attn_kernel(const unsigned short* __restrict__ Q, const unsigned short* __restrict__ K,
            const unsigned short* __restrict__ VT, unsigned short* __restrict__ O) {
  __shared__ __align__(16) unsigned short qp_s[64][72];    // Q tile / P^T / O staging
  __shared__ __align__(16) unsigned short k_s[2][64 * 64]; // row-major 64x64, swizzled
  __shared__ __align__(16) unsigned short vt_s[2][64 * 64];

  const int tid = threadIdx.x;
  const int lane = tid & 63;
  const int w = tid >> 6;              // 0..3
  const int m16 = lane & 15;
  const int quad = lane >> 4;
  const int swz = m16 & 7;
  const int pc0 = quad ^ swz;          // physical chunk for k-step 0
  const int pc1 = pc0 ^ 4;             // k-step 1

  const int x = blockIdx.x;
  const int qt = 31 - (x >> 5);        // heavy q-tiles first
  const int bh = x & 31;
  const int b = bh >> 4, h = bh & 15;
  const int q0 = qt * 64;

  const unsigned short* Qb = Q + ((size_t)b * T_ + q0) * D_ + h * HD_;
  const unsigned short* Kb = K + (size_t)b * T_ * D_ + h * HD_;
  const unsigned short* VTb = VT + ((size_t)b * H_ + h) * HD_ * T_;

  // stage Q tile (manual, padded LDS): 64 rows x 128B
#pragma unroll
  for (int i = 0; i < 2; i++) {
    int idx = tid + i * 256;
    int r = idx >> 3, c = idx & 7;
    *(bf16x8*)&qp_s[r][c * 8] = *(const bf16x8*)(Qb + (size_t)r * D_ + c * 8);
  }

  // async stage of K/VT tile kt: wave w covers rows w*16..w*16+15 (2 instr each)
  auto stage_kv = [&](int kt, int bs) {
    int rs = lane >> 3;                       // 0..7
    int cs = ((lane & 7) ^ rs) * 8;           // XOR-swizzled source chunk
    int gr = w * 16 + rs;
    ld_g2l_16(Kb + (size_t)(kt * 64 + gr) * D_ + cs,      &k_s[bs][(w * 16) * 64]);
    ld_g2l_16(Kb + (size_t)(kt * 64 + gr + 8) * D_ + cs,  &k_s[bs][(w * 16 + 8) * 64]);
    ld_g2l_16(VTb + (size_t)gr * T_ + kt * 64 + cs,       &vt_s[bs][(w * 16) * 64]);
    ld_g2l_16(VTb + (size_t)(gr + 8) * T_ + kt * 64 + cs, &vt_s[bs][(w * 16 + 8) * 64]);
  };

  f32x4 o_acc[4];
#pragma unroll
  for (int dt = 0; dt < 4; dt++) o_acc[dt] = (f32x4){0.f, 0.f, 0.f, 0.f};
  float m_i = -1e30f, l_i = 0.f;
  const int rg = q0 + w * 16 + m16;

  stage_kv(0, 0);
  __syncthreads();   // publishes Q tile + first K/V tile
  bf16x8 q_frag[2];
  q_frag[0] = *(const bf16x8*)&qp_s[w * 16 + m16][quad * 8];
  q_frag[1] = *(const bf16x8*)&qp_s[w * 16 + m16][32 + quad * 8];

  for (int t = 0; t <= qt; t++) {
    int cur = t & 1;
    if (t < qt) stage_kv(t + 1, cur ^ 1);   // DMA flies under compute

    const unsigned short* kc = &k_s[cur][0];
    const unsigned short* vc = &vt_s[cur][0];
    // S^T = K Q^T
    f32x4 sf[4];
    __builtin_amdgcn_s_setprio(1);
#pragma unroll
    for (int jt = 0; jt < 4; jt++) {
      bf16x8 a0 = *(const bf16x8*)&kc[(jt * 16 + m16) * 64 + pc0 * 8];
      bf16x8 a1 = *(const bf16x8*)&kc[(jt * 16 + m16) * 64 + pc1 * 8];
      f32x4 acc = (f32x4){0.f, 0.f, 0.f, 0.f};
      acc = __builtin_amdgcn_mfma_f32_16x16x32_bf16(a0, q_frag[0], acc, 0, 0, 0);
      acc = __builtin_amdgcn_mfma_f32_16x16x32_bf16(a1, q_frag[1], acc, 0, 0, 0);
      sf[jt] = acc;
    }
    __builtin_amdgcn_s_setprio(0);
    if (t == qt) {                       // diagonal tile: causal mask
#pragma unroll
      for (int jt = 0; jt < 4; jt++)
#pragma unroll
        for (int reg = 0; reg < 4; reg++) {
          int jg = t * 64 + jt * 16 + quad * 4 + reg;
          if (jg > rg) sf[jt][reg] = -1e30f;
        }
    }
    // online softmax in base-2 (per-lane row, 2 cross-quad shfls)
    float mx = sf[0][0];
#pragma unroll
    for (int jt = 0; jt < 4; jt++)
#pragma unroll
      for (int reg = 0; reg < 4; reg++) mx = fmaxf(mx, sf[jt][reg]);
    mx = fmaxf(mx, __shfl_xor(mx, 16, 64));
    mx = fmaxf(mx, __shfl_xor(mx, 32, 64));
    // T13 defer-max: skip O-rescale while max grows < 8 (P bounded by 2^8)
    if (!__all(mx <= m_i + 8.f)) {
      float mn = fmaxf(m_i, mx);
      float alpha = exp2f(m_i - mn);
      l_i *= alpha;
#pragma unroll
      for (int dt = 0; dt < 4; dt++)
#pragma unroll
        for (int reg = 0; reg < 4; reg++) o_acc[dt][reg] *= alpha;
      m_i = mn;
    }
    float lt = 0.f;
    float p[4][4];
#pragma unroll
    for (int jt = 0; jt < 4; jt++)
#pragma unroll
      for (int reg = 0; reg < 4; reg++) {
        p[jt][reg] = exp2f(sf[jt][reg] - m_i);
        lt += p[jt][reg];
      }
    // P^T rows -> qp_s (wave-private)
#pragma unroll
    for (int jt = 0; jt < 4; jt++) {
      unsigned short pk[4] = {f2b(p[jt][0]), f2b(p[jt][1]), f2b(p[jt][2]), f2b(p[jt][3])};
      *(uint2*)&qp_s[w * 16 + m16][jt * 16 + quad * 4] = *(uint2*)pk;
    }
    bf16x8 bp0 = *(const bf16x8*)&qp_s[w * 16 + m16][quad * 8];
    bf16x8 bp1 = *(const bf16x8*)&qp_s[w * 16 + m16][32 + quad * 8];
    // O^T += V^T P^T
    __builtin_amdgcn_s_setprio(1);
#pragma unroll
    for (int dt = 0; dt < 4; dt++) {
      int rowd = dt * 16 + m16;
      bf16x8 a0 = *(const bf16x8*)&vc[rowd * 64 + pc0 * 8];
      bf16x8 a1 = *(const bf16x8*)&vc[rowd * 64 + pc1 * 8];
      o_acc[dt] = __builtin_amdgcn_mfma_f32_16x16x32_bf16(a0, bp0, o_acc[dt], 0, 0, 0);
      o_acc[dt] = __builtin_amdgcn_mfma_f32_16x16x32_bf16(a1, bp1, o_acc[dt], 0, 0, 0);
    }
    __builtin_amdgcn_s_setprio(0);
    // l-reduction deferred so the 2 shfls overlap PV MFMAs
    lt += __shfl_xor(lt, 16, 64);
    lt += __shfl_xor(lt, 32, 64);
    l_i += lt;
    __syncthreads();   // publishes next tile, protects buffer reuse
  }

  // epilogue: normalize, transpose via LDS, coalesced stores
  float inv = 1.f / l_i;
#pragma unroll
  for (int dt = 0; dt < 4; dt++) {
    unsigned short ok[4];
#pragma unroll
    for (int reg = 0; reg < 4; reg++) ok[reg] = f2b(o_acc[dt][reg] * inv);
    *(uint2*)&qp_s[w * 16 + m16][dt * 16 + quad * 4] = *(uint2*)ok;
  }
  __syncthreads();
  unsigned short* Ob = O + ((size_t)b * T_ + q0) * D_ + h * HD_;
#pragma unroll
  for (int i = 0; i < 2; i++) {
    int idx = tid + i * 256;
    int r = idx >> 3, c = idx & 7;
    *(bf16x8*)(Ob + (size_t)r * D_ + c * 8) = *(const bf16x8*)&qp_s[r][c * 8];
  }
}

extern "C" void kernel_launch(void* const* d_in, const int* in_sizes, int n_in,
                              void* d_out, int out_size, void* d_ws, size_t ws_size,
                              hipStream_t stream) {
  const float* x    = (const float*)d_in[0];
  const float* wq   = (const float*)d_in[1];
  const float* wk   = (const float*)d_in[2];
  const float* wv   = (const float*)d_in[3];
  const float* wo   = (const float*)d_in[4];
  const float* cosT = (const float*)d_in[5];
  const float* sinT = (const float*)d_in[6];
  float* out = (float*)d_out;

  const size_t NTOK = (size_t)B_ * T_;   // 4096
  const size_t SZ   = NTOK * D_;         // 4M elements
  unsigned short* xb   = (unsigned short*)d_ws;   // 8 MB (dead after gemm_qkv)
  unsigned short* Wp   = xb + SZ;                 // 8 MB (wq|wk|wv|wo)
  unsigned short* QKVh = Wp + 4 * 1048576;        // 24 MB (Q|K|V)
  unsigned short* Ab   = QKVh + 3 * SZ;           // 8 MB
  unsigned short* VTb  = xb;                      // reuse xb for V^T

  cast_all<<<4096, 256, 0, stream>>>(x, wq, wk, wv, wo, xb, Wp);
  gemm_qkv<<<dim3(24, 32), 256, 0, stream>>>(xb, Wp, QKVh, cosT, sinT);
  vtrans<<<dim3(32, 16, 2), 256, 0, stream>>>(QKVh + 2 * SZ, VTb);
  attn_kernel<<<1024, 256, 0, stream>>>(QKVh, QKVh + SZ, VTb, Ab);
  gemm_out<<<dim3(8, 64), 256, 0, stream>>>(Ab, Wp + 3 * 1048576, out);
}